// Round 7
// baseline (259.356 us; speedup 1.0000x reference)
//
#include <hip/hip_runtime.h>
#include <hip/hip_bf16.h>

#define IN_DIM 256
#define OUT_DIM 256
#define NHEADS 4
#define NEG_SLOPE 0.2f
#define ELLW 48
#define OVFCAP (1 << 18)

typedef unsigned short u16;
typedef __attribute__((ext_vector_type(8))) short short8;
typedef __attribute__((ext_vector_type(4))) float f32x4;

__device__ __forceinline__ float bf2f(u16 v) {
    return __uint_as_float(((unsigned int)v) << 16);
}
__device__ __forceinline__ u16 f2bf(float f) {
    unsigned int b = __float_as_uint(f);
    b += 0x7FFFu + ((b >> 16) & 1u);   // RNE
    return (u16)(b >> 16);
}
// unpack 4 consecutive bf16 (uint2) -> float4
__device__ __forceinline__ float4 bf4(uint2 p) {
    float4 r;
    r.x = __uint_as_float(p.x << 16);
    r.y = __uint_as_float(p.x & 0xFFFF0000u);
    r.z = __uint_as_float(p.y << 16);
    r.w = __uint_as_float(p.y & 0xFFFF0000u);
    return r;
}
__device__ __forceinline__ float lrelu(float v) { return v > 0.f ? v : NEG_SLOPE * v; }

// per-wave dtype detection (all waves agree; one broadcast 128B read)
__device__ __forceinline__ int detectbf(const void* x) {
    int lane = threadIdx.x & 63;
    u16 v = ((const u16*)x)[2 * lane];
    int e = (v >> 7) & 0xFF;
    int sane = (e >= 118 && e <= 137) || ((v & 0x7FFFu) == 0);
    return __popcll(__ballot(sane)) >= 48;
}
__device__ __forceinline__ int detect64(const void* eidx) {
    int lane = threadIdx.x & 63;
    return __ballot(((const int*)eidx)[2 * lane + 1] == 0) == ~0ull;
}

__device__ __forceinline__ void eread(const void* e, int is64, int i, int E, int& s, int& d) {
    if (is64) {
        const long long* p = (const long long*)e;
        s = (int)p[i]; d = (int)p[(size_t)E + i];
    } else {
        const int* p = (const int*)e;
        s = p[i]; d = p[(size_t)E + i];
    }
}

// ---------- lean prep: att conv (block 0) | W transpose conv (1..128) | ELL build (129..) ----------
__global__ __launch_bounds__(256) void k_prep(const void* x, const void* eidx,
                                              const void* W, const void* as, const void* ad,
                                              u16* Wtb, float* asf, float* adf,
                                              int* cnt, int* ell, int* ovf, int n, int E) {
    int b = blockIdx.x, t = threadIdx.x;
    if (b == 0) {
        int isb = detectbf(x);
        asf[t] = isb ? bf2f(((const u16*)as)[t]) : ((const float*)as)[t];
        adf[t] = isb ? bf2f(((const u16*)ad)[t]) : ((const float*)ad)[t];
    } else if (b <= 128) {
        int isb = detectbf(x);
        int base = (b - 1) * 512;
#pragma unroll
        for (int j = 0; j < 2; ++j) {
            int i = base + t + j * 256;
            int nOut = i >> 8, k = i & 255;
            float w = isb ? bf2f(((const u16*)W)[(size_t)k * OUT_DIM + nOut])
                          : ((const float*)W)[(size_t)k * OUT_DIM + nOut];
            Wtb[i] = f2bf(w);
        }
    } else {
        const int is64 = detect64(eidx);
        int i = (b - 129) * 256 + t;
        if (i < E) {
            int s, d;
            eread(eidx, is64, i, E, s, d);
            int pos = atomicAdd(&cnt[d], 1);
            if (pos < ELLW) {
                ell[d * ELLW + pos] = s;
            } else {
                int o = atomicAdd(&cnt[n], 1) & (OVFCAP - 1);
                ovf[2 * o] = d; ovf[2 * o + 1] = s;
            }
        }
    }
}

// ---------- pure MFMA GEMM: block tile 128 rows x 256 cols + fused att-dot epilogue ----------
// 4 waves (2x2), wave tile 64x128 (4x8 of 16x16x32); x read exactly once
__global__ __launch_bounds__(256, 2) void k_gemm(const void* __restrict__ x,
                                                 const u16* __restrict__ Wtb,
                                                 const float* __restrict__ asf,
                                                 const float* __restrict__ adf,
                                                 u16* __restrict__ xpb,
                                                 float* __restrict__ a_src,
                                                 float* __restrict__ a_dst, int n) {
    __shared__ u16 As[128][32];   // 8 KB
    __shared__ u16 Bs[256][32];   // 16 KB
    const int isb = detectbf(x);
    const int t = threadIdx.x;
    const int row0 = blockIdx.x * 128;
    const int wave = t >> 6, lane = t & 63;
    const int q = lane >> 4, l16 = lane & 15;
    const int wm = (wave >> 1) * 64, wn = (wave & 1) * 128;
    f32x4 acc[4][8];
#pragma unroll
    for (int a = 0; a < 4; ++a)
#pragma unroll
        for (int b = 0; b < 8; ++b) acc[a][b] = (f32x4){0.f, 0.f, 0.f, 0.f};

    const int sr = t >> 3;        // 0..31
    const int sk = (t & 7) * 4;   // 0,4,...,28

    for (int k0 = 0; k0 < IN_DIM; k0 += 32) {
#pragma unroll
        for (int i = 0; i < 4; ++i) {
            int rr = sr + i * 32;
            int grow = row0 + rr; if (grow >= n) grow = n - 1;   // clamp; stores guarded
            uint2 pk;
            if (isb) {
                pk = *(const uint2*)((const u16*)x + (size_t)grow * IN_DIM + k0 + sk);
            } else {
                const float* xf = (const float*)x + (size_t)grow * IN_DIM + k0 + sk;
                float4 v = *(const float4*)xf;
                pk.x = ((unsigned)f2bf(v.y) << 16) | f2bf(v.x);
                pk.y = ((unsigned)f2bf(v.w) << 16) | f2bf(v.z);
            }
            *(uint2*)&As[rr][sk] = pk;
        }
#pragma unroll
        for (int i = 0; i < 8; ++i) {
            int rr = sr + i * 32;
            *(uint2*)&Bs[rr][sk] = *(const uint2*)(Wtb + (size_t)rr * IN_DIM + k0 + sk);
        }
        __syncthreads();
        short8 af[4], bfr[8];
#pragma unroll
        for (int mt = 0; mt < 4; ++mt)
            af[mt] = *(const short8*)&As[wm + mt * 16 + l16][q * 8];
#pragma unroll
        for (int nt = 0; nt < 8; ++nt)
            bfr[nt] = *(const short8*)&Bs[wn + nt * 16 + l16][q * 8];
#pragma unroll
        for (int mt = 0; mt < 4; ++mt)
#pragma unroll
            for (int nt = 0; nt < 8; ++nt)
                acc[mt][nt] = __builtin_amdgcn_mfma_f32_16x16x32_bf16(
                    af[mt], bfr[nt], acc[mt][nt], 0, 0, 0);
        __syncthreads();
    }
    // C/D layout: col = lane&15, row = quad*4 + reg ; store bf16
#pragma unroll
    for (int mt = 0; mt < 4; ++mt) {
#pragma unroll
        for (int nt = 0; nt < 8; ++nt) {
            int col = wn + nt * 16 + l16;
#pragma unroll
            for (int r = 0; r < 4; ++r) {
                int row = row0 + wm + mt * 16 + q * 4 + r;
                if (row < n) xpb[(size_t)row * OUT_DIM + col] = f2bf(acc[mt][nt][r]);
            }
        }
    }
    // fused att-dot: wave's 128 cols = heads h0, h0+1
    float asv[8], adv[8];
#pragma unroll
    for (int nt = 0; nt < 8; ++nt) {
        int col = wn + nt * 16 + l16;
        asv[nt] = asf[col]; adv[nt] = adf[col];
    }
    int h0 = wn >> 6;
#pragma unroll
    for (int mt = 0; mt < 4; ++mt) {
#pragma unroll
        for (int r = 0; r < 4; ++r) {
            float vs0 = acc[mt][0][r] * asv[0] + acc[mt][1][r] * asv[1]
                      + acc[mt][2][r] * asv[2] + acc[mt][3][r] * asv[3];
            float vd0 = acc[mt][0][r] * adv[0] + acc[mt][1][r] * adv[1]
                      + acc[mt][2][r] * adv[2] + acc[mt][3][r] * adv[3];
            float vs1 = acc[mt][4][r] * asv[4] + acc[mt][5][r] * asv[5]
                      + acc[mt][6][r] * asv[6] + acc[mt][7][r] * asv[7];
            float vd1 = acc[mt][4][r] * adv[4] + acc[mt][5][r] * adv[5]
                      + acc[mt][6][r] * adv[6] + acc[mt][7][r] * adv[7];
#pragma unroll
            for (int m = 1; m < 16; m <<= 1) {
                vs0 += __shfl_xor(vs0, m); vd0 += __shfl_xor(vd0, m);
                vs1 += __shfl_xor(vs1, m); vd1 += __shfl_xor(vd1, m);
            }
            if (l16 == 0) {
                int row = row0 + wm + mt * 16 + q * 4 + r;
                if (row < n) {
                    a_src[row * NHEADS + h0] = vs0;
                    a_dst[row * NHEADS + h0] = vd0;
                    a_src[row * NHEADS + h0 + 1] = vs1;
                    a_dst[row * NHEADS + h0 + 1] = vd1;
                }
            }
        }
    }
}

// ---------- wave-per-dst softmax gather over ELL (no max-rescale: logits bounded) ----------
__global__ __launch_bounds__(256) void k_agg(const int* __restrict__ cnt,
                                             const int* __restrict__ ell,
                                             const int* __restrict__ ovf,
                                             const float* __restrict__ a_src,
                                             const float* __restrict__ a_dst,
                                             const u16* __restrict__ xpb,
                                             void* out, const void* x, int n) {
    int isb = detectbf(x);
    int d = (blockIdx.x * 256 + threadIdx.x) >> 6;
    int lane = threadIdx.x & 63;
    if (d >= n) return;
    int h = lane >> 4;
    int deg = cnt[d];
    int m = deg < ELLW ? deg : ELLW;
    const int* row = ell + d * ELLW;
    float ad = a_dst[d * NHEADS + h];
    // self-loop
    float vsf = fminf(lrelu(a_src[d * NHEADS + h] + ad), 80.f);
    float wsf = __expf(vsf);
    float4 xs = bf4(((const uint2*)(xpb + (size_t)d * OUT_DIM))[lane]);
    float4 acc;
    acc.x = wsf * xs.x; acc.y = wsf * xs.y; acc.z = wsf * xs.z; acc.w = wsf * xs.w;
    float den = wsf;
    int e = 0;
    for (; e + 8 <= m; e += 8) {
        int s[8]; uint2 p[8]; float w[8];
#pragma unroll
        for (int j = 0; j < 8; ++j) s[j] = row[e + j];
#pragma unroll
        for (int j = 0; j < 8; ++j)
            p[j] = ((const uint2*)(xpb + (size_t)s[j] * OUT_DIM))[lane];
#pragma unroll
        for (int j = 0; j < 8; ++j) {
            float v = fminf(lrelu(a_src[s[j] * NHEADS + h] + ad), 80.f);
            w[j] = __expf(v);
        }
#pragma unroll
        for (int j = 0; j < 8; ++j) {
            float4 xv = bf4(p[j]);
            acc.x += w[j] * xv.x; acc.y += w[j] * xv.y;
            acc.z += w[j] * xv.z; acc.w += w[j] * xv.w;
            den += w[j];
        }
    }
    for (; e < m; ++e) {
        int s = row[e];
        float v = fminf(lrelu(a_src[s * NHEADS + h] + ad), 80.f);
        float w = __expf(v);
        float4 xv = bf4(((const uint2*)(xpb + (size_t)s * OUT_DIM))[lane]);
        acc.x += w * xv.x; acc.y += w * xv.y; acc.z += w * xv.z; acc.w += w * xv.w;
        den += w;
    }
    if (deg > ELLW) {           // overflow edges (statistically never for Poisson(16))
        int movf = cnt[n]; if (movf > OVFCAP) movf = OVFCAP;
        for (int i = 0; i < movf; ++i) {
            if (ovf[2 * i] == d) {
                int s = ovf[2 * i + 1];
                float v = fminf(lrelu(a_src[s * NHEADS + h] + ad), 80.f);
                float w = __expf(v);
                float4 xv = bf4(((const uint2*)(xpb + (size_t)s * OUT_DIM))[lane]);
                acc.x += w * xv.x; acc.y += w * xv.y; acc.z += w * xv.z; acc.w += w * xv.w;
                den += w;
            }
        }
    }
    float rd = 1.f / den;
    float o0 = fmaxf(acc.x * rd, 0.f);
    float o1 = fmaxf(acc.y * rd, 0.f);
    float o2 = fmaxf(acc.z * rd, 0.f);
    float o3 = fmaxf(acc.w * rd, 0.f);
    size_t idx = (size_t)d * OUT_DIM + lane * 4;
    if (isb) {
        u16 p4[4] = {f2bf(o0), f2bf(o1), f2bf(o2), f2bf(o3)};
        *(uint2*)((u16*)out + idx) = *(const uint2*)p4;
    } else {
        float p4[4] = {o0, o1, o2, o3};
        *(float4*)((float*)out + idx) = *(const float4*)p4;
    }
}

extern "C" void kernel_launch(void* const* d_in, const int* in_sizes, int n_in,
                              void* d_out, int out_size, void* d_ws, size_t ws_size,
                              hipStream_t stream) {
    const void* x    = d_in[0];
    const void* eidx = d_in[1];
    const void* W    = d_in[2];
    const void* as   = d_in[3];
    const void* ad   = d_in[4];
    int n = in_sizes[0] / IN_DIM;   // 50000
    int E = in_sizes[1] / 2;        // 800000

    char* ws = (char*)d_ws;
    size_t off_b = 0;
    auto alloc = [&](size_t bytes) -> void* {
        void* p = ws + off_b;
        off_b += (bytes + 255) & ~(size_t)255;
        return p;
    };
    u16*   Wtb    = (u16*)alloc((size_t)IN_DIM * OUT_DIM * 2);
    float* asf    = (float*)alloc(256 * 4);
    float* adf    = (float*)alloc(256 * 4);
    u16*   xpb    = (u16*)alloc((size_t)n * OUT_DIM * 2);
    float* a_src  = (float*)alloc((size_t)n * NHEADS * 4);
    float* a_dst  = (float*)alloc((size_t)n * NHEADS * 4);
    int*   cnt    = (int*)alloc((size_t)(n + 1) * 4);   // +1: overflow counter
    int*   ell    = (int*)alloc((size_t)n * ELLW * 4);
    int*   ovf    = (int*)alloc((size_t)OVFCAP * 8);

    int ngemm = (n + 127) / 128;      // 391
    int nell  = (E + 255) / 256;      // 3125

    hipMemsetAsync(cnt, 0, (size_t)(n + 1) * 4, stream);

    hipLaunchKernelGGL(k_prep, dim3(129 + nell), dim3(256), 0, stream,
                       x, eidx, W, as, ad, Wtb, asf, adf, cnt, ell, ovf, n, E);
    hipLaunchKernelGGL(k_gemm, dim3(ngemm), dim3(256), 0, stream,
                       x, Wtb, asf, adf, xpb, a_src, a_dst, n);
    hipLaunchKernelGGL(k_agg, dim3((n + 3) / 4), dim3(256), 0, stream,
                       cnt, ell, ovf, a_src, a_dst, xpb, d_out, x, n);
}

// Round 8
// 241.148 us; speedup vs baseline: 1.0755x; 1.0755x over previous
//
#include <hip/hip_runtime.h>
#include <hip/hip_bf16.h>

#define IN_DIM 256
#define OUT_DIM 256
#define NHEADS 4
#define NEG_SLOPE 0.2f
#define ELLW 48
#define OVFCAP (1 << 18)

typedef unsigned short u16;
typedef __attribute__((ext_vector_type(8))) short short8;
typedef __attribute__((ext_vector_type(4))) float f32x4;

__device__ __forceinline__ float bf2f(u16 v) {
    return __uint_as_float(((unsigned int)v) << 16);
}
__device__ __forceinline__ u16 f2bf(float f) {
    unsigned int b = __float_as_uint(f);
    b += 0x7FFFu + ((b >> 16) & 1u);   // RNE
    return (u16)(b >> 16);
}
// unpack 4 consecutive bf16 (uint2) -> float4
__device__ __forceinline__ float4 bf4(unsigned int a, unsigned int b) {
    float4 r;
    r.x = __uint_as_float(a << 16);
    r.y = __uint_as_float(a & 0xFFFF0000u);
    r.z = __uint_as_float(b << 16);
    r.w = __uint_as_float(b & 0xFFFF0000u);
    return r;
}
__device__ __forceinline__ float lrelu(float v) { return v > 0.f ? v : NEG_SLOPE * v; }

// per-wave dtype detection (all waves agree; one broadcast 128B read)
__device__ __forceinline__ int detectbf(const void* x) {
    int lane = threadIdx.x & 63;
    u16 v = ((const u16*)x)[2 * lane];
    int e = (v >> 7) & 0xFF;
    int sane = (e >= 118 && e <= 137) || ((v & 0x7FFFu) == 0);
    return __popcll(__ballot(sane)) >= 48;
}
__device__ __forceinline__ int detect64(const void* eidx) {
    int lane = threadIdx.x & 63;
    return __ballot(((const int*)eidx)[2 * lane + 1] == 0) == ~0ull;
}

__device__ __forceinline__ void eread(const void* e, int is64, int i, int E, int& s, int& d) {
    if (is64) {
        const long long* p = (const long long*)e;
        s = (int)p[i]; d = (int)p[(size_t)E + i];
    } else {
        const int* p = (const int*)e;
        s = p[i]; d = p[(size_t)E + i];
    }
}

// ---------- conv + zero: att (block 0) | W transpose (1..128) | zero cnt (129..) ----------
__global__ __launch_bounds__(256) void k_conv(const void* x, const void* W,
                                              const void* as, const void* ad,
                                              u16* Wtb, float* asf, float* adf,
                                              int* cnt, int n) {
    int b = blockIdx.x, t = threadIdx.x;
    if (b == 0) {
        int isb = detectbf(x);
        asf[t] = isb ? bf2f(((const u16*)as)[t]) : ((const float*)as)[t];
        adf[t] = isb ? bf2f(((const u16*)ad)[t]) : ((const float*)ad)[t];
    } else if (b <= 128) {
        int isb = detectbf(x);
        int base = (b - 1) * 512;
#pragma unroll
        for (int j = 0; j < 2; ++j) {
            int i = base + t + j * 256;
            int nOut = i >> 8, k = i & 255;
            float w = isb ? bf2f(((const u16*)W)[(size_t)k * OUT_DIM + nOut])
                          : ((const float*)W)[(size_t)k * OUT_DIM + nOut];
            Wtb[i] = f2bf(w);
        }
    } else {
        int i = (b - 129) * 256 + t;
        if (i <= n) cnt[i] = 0;     // includes overflow counter at cnt[n]
    }
}

// ---------- merged: [0..ngemm) MFMA GEMM 128x256 + att-dot | rest: ELL build ----------
// merge rationale: ELL scatter is latency-bound and hides behind GEMM's MFMA phase (R6: 82us)
__global__ __launch_bounds__(256, 2) void k_main(const void* __restrict__ x,
                                                 const void* __restrict__ eidx,
                                                 const u16* __restrict__ Wtb,
                                                 const float* __restrict__ asf,
                                                 const float* __restrict__ adf,
                                                 u16* __restrict__ xpb,
                                                 float* __restrict__ a_src,
                                                 float* __restrict__ a_dst,
                                                 int* __restrict__ cnt,
                                                 int* __restrict__ ell,
                                                 int* __restrict__ ovf,
                                                 int n, int E, int ngemm) {
    if ((int)blockIdx.x < ngemm) {
        __shared__ u16 As[128][32];   // 8 KB
        __shared__ u16 Bs[256][32];   // 16 KB
        const int isb = detectbf(x);
        const int t = threadIdx.x;
        const int row0 = blockIdx.x * 128;
        const int wave = t >> 6, lane = t & 63;
        const int q = lane >> 4, l16 = lane & 15;
        const int wm = (wave >> 1) * 64, wn = (wave & 1) * 128;
        f32x4 acc[4][8];
#pragma unroll
        for (int a = 0; a < 4; ++a)
#pragma unroll
            for (int b = 0; b < 8; ++b) acc[a][b] = (f32x4){0.f, 0.f, 0.f, 0.f};

        const int sr = t >> 3;        // 0..31
        const int sk = (t & 7) * 4;   // 0,4,...,28

        for (int k0 = 0; k0 < IN_DIM; k0 += 32) {
#pragma unroll
            for (int i = 0; i < 4; ++i) {
                int rr = sr + i * 32;
                int grow = row0 + rr; if (grow >= n) grow = n - 1;   // clamp; stores guarded
                uint2 pk;
                if (isb) {
                    pk = *(const uint2*)((const u16*)x + (size_t)grow * IN_DIM + k0 + sk);
                } else {
                    const float* xf = (const float*)x + (size_t)grow * IN_DIM + k0 + sk;
                    float4 v = *(const float4*)xf;
                    pk.x = ((unsigned)f2bf(v.y) << 16) | f2bf(v.x);
                    pk.y = ((unsigned)f2bf(v.w) << 16) | f2bf(v.z);
                }
                *(uint2*)&As[rr][sk] = pk;
            }
#pragma unroll
            for (int i = 0; i < 8; ++i) {
                int rr = sr + i * 32;
                *(uint2*)&Bs[rr][sk] = *(const uint2*)(Wtb + (size_t)rr * IN_DIM + k0 + sk);
            }
            __syncthreads();
            short8 af[4], bfr[8];
#pragma unroll
            for (int mt = 0; mt < 4; ++mt)
                af[mt] = *(const short8*)&As[wm + mt * 16 + l16][q * 8];
#pragma unroll
            for (int nt = 0; nt < 8; ++nt)
                bfr[nt] = *(const short8*)&Bs[wn + nt * 16 + l16][q * 8];
#pragma unroll
            for (int mt = 0; mt < 4; ++mt)
#pragma unroll
                for (int nt = 0; nt < 8; ++nt)
                    acc[mt][nt] = __builtin_amdgcn_mfma_f32_16x16x32_bf16(
                        af[mt], bfr[nt], acc[mt][nt], 0, 0, 0);
            __syncthreads();
        }
        // C/D layout: col = lane&15, row = quad*4 + reg ; store bf16
#pragma unroll
        for (int mt = 0; mt < 4; ++mt) {
#pragma unroll
            for (int nt = 0; nt < 8; ++nt) {
                int col = wn + nt * 16 + l16;
#pragma unroll
                for (int r = 0; r < 4; ++r) {
                    int row = row0 + wm + mt * 16 + q * 4 + r;
                    if (row < n) xpb[(size_t)row * OUT_DIM + col] = f2bf(acc[mt][nt][r]);
                }
            }
        }
        // fused att-dot: wave's 128 cols = heads h0, h0+1
        float asv[8], adv[8];
#pragma unroll
        for (int nt = 0; nt < 8; ++nt) {
            int col = wn + nt * 16 + l16;
            asv[nt] = asf[col]; adv[nt] = adf[col];
        }
        int h0 = wn >> 6;
#pragma unroll
        for (int mt = 0; mt < 4; ++mt) {
#pragma unroll
            for (int r = 0; r < 4; ++r) {
                float vs0 = acc[mt][0][r] * asv[0] + acc[mt][1][r] * asv[1]
                          + acc[mt][2][r] * asv[2] + acc[mt][3][r] * asv[3];
                float vd0 = acc[mt][0][r] * adv[0] + acc[mt][1][r] * adv[1]
                          + acc[mt][2][r] * adv[2] + acc[mt][3][r] * adv[3];
                float vs1 = acc[mt][4][r] * asv[4] + acc[mt][5][r] * asv[5]
                          + acc[mt][6][r] * asv[6] + acc[mt][7][r] * asv[7];
                float vd1 = acc[mt][4][r] * adv[4] + acc[mt][5][r] * adv[5]
                          + acc[mt][6][r] * adv[6] + acc[mt][7][r] * adv[7];
#pragma unroll
                for (int m = 1; m < 16; m <<= 1) {
                    vs0 += __shfl_xor(vs0, m); vd0 += __shfl_xor(vd0, m);
                    vs1 += __shfl_xor(vs1, m); vd1 += __shfl_xor(vd1, m);
                }
                if (l16 == 0) {
                    int row = row0 + wm + mt * 16 + q * 4 + r;
                    if (row < n) {
                        a_src[row * NHEADS + h0] = vs0;
                        a_dst[row * NHEADS + h0] = vd0;
                        a_src[row * NHEADS + h0 + 1] = vs1;
                        a_dst[row * NHEADS + h0 + 1] = vd1;
                    }
                }
            }
        }
    } else {
        // ---- ELL build: one edge per thread
        const int is64 = detect64(eidx);
        int i = ((int)blockIdx.x - ngemm) * 256 + threadIdx.x;
        if (i < E) {
            int s, d;
            eread(eidx, is64, i, E, s, d);
            int pos = atomicAdd(&cnt[d], 1);
            if (pos < ELLW) {
                ell[d * ELLW + pos] = s;
            } else {
                int o = atomicAdd(&cnt[n], 1) & (OVFCAP - 1);
                ovf[2 * o] = d; ovf[2 * o + 1] = s;
            }
        }
    }
}

// ---------- agg: 2 dsts per wave (one per half-wave), 16B/lane gathers ----------
__global__ __launch_bounds__(256) void k_agg(const int* __restrict__ cnt,
                                             const int* __restrict__ ell,
                                             const int* __restrict__ ovf,
                                             const float* __restrict__ a_src,
                                             const float* __restrict__ a_dst,
                                             const u16* __restrict__ xpb,
                                             void* out, const void* x, int n) {
    int isb = detectbf(x);
    int wid = (blockIdx.x * 256 + threadIdx.x) >> 6;
    int lane = threadIdx.x & 63;
    int hl = lane & 31;                 // lane within half-wave
    int d = wid * 2 + (lane >> 5);      // dst for this half-wave
    if (d >= n) return;
    int h = hl >> 3;                    // 8 lanes x 8 cols = 64 cols per head
    int deg = cnt[d];
    int m = deg < ELLW ? deg : ELLW;
    const int* row = ell + d * ELLW;
    float ad = a_dst[d * NHEADS + h];
    // self-loop
    float vsf = fminf(lrelu(a_src[d * NHEADS + h] + ad), 80.f);
    float wsf = __expf(vsf);
    uint4 ps = ((const uint4*)(xpb + (size_t)d * OUT_DIM))[hl];
    float4 xl = bf4(ps.x, ps.y), xh = bf4(ps.z, ps.w);
    float4 accl, acch;
    accl.x = wsf * xl.x; accl.y = wsf * xl.y; accl.z = wsf * xl.z; accl.w = wsf * xl.w;
    acch.x = wsf * xh.x; acch.y = wsf * xh.y; acch.z = wsf * xh.z; acch.w = wsf * xh.w;
    float den = wsf;
    int e = 0;
    for (; e + 8 <= m; e += 8) {
        int s[8]; uint4 p[8]; float w[8];
#pragma unroll
        for (int j = 0; j < 8; ++j) s[j] = row[e + j];
#pragma unroll
        for (int j = 0; j < 8; ++j)
            p[j] = ((const uint4*)(xpb + (size_t)s[j] * OUT_DIM))[hl];
#pragma unroll
        for (int j = 0; j < 8; ++j) {
            float v = fminf(lrelu(a_src[s[j] * NHEADS + h] + ad), 80.f);
            w[j] = __expf(v);
        }
#pragma unroll
        for (int j = 0; j < 8; ++j) {
            float4 yl = bf4(p[j].x, p[j].y), yh = bf4(p[j].z, p[j].w);
            accl.x += w[j] * yl.x; accl.y += w[j] * yl.y;
            accl.z += w[j] * yl.z; accl.w += w[j] * yl.w;
            acch.x += w[j] * yh.x; acch.y += w[j] * yh.y;
            acch.z += w[j] * yh.z; acch.w += w[j] * yh.w;
            den += w[j];
        }
    }
    for (; e < m; ++e) {
        int s = row[e];
        float v = fminf(lrelu(a_src[s * NHEADS + h] + ad), 80.f);
        float w = __expf(v);
        uint4 p = ((const uint4*)(xpb + (size_t)s * OUT_DIM))[hl];
        float4 yl = bf4(p.x, p.y), yh = bf4(p.z, p.w);
        accl.x += w * yl.x; accl.y += w * yl.y; accl.z += w * yl.z; accl.w += w * yl.w;
        acch.x += w * yh.x; acch.y += w * yh.y; acch.z += w * yh.z; acch.w += w * yh.w;
        den += w;
    }
    if (deg > ELLW) {           // overflow edges (statistically never for Poisson(16))
        int movf = cnt[n]; if (movf > OVFCAP) movf = OVFCAP;
        for (int i = 0; i < movf; ++i) {
            if (ovf[2 * i] == d) {
                int s = ovf[2 * i + 1];
                float v = fminf(lrelu(a_src[s * NHEADS + h] + ad), 80.f);
                float w = __expf(v);
                uint4 p = ((const uint4*)(xpb + (size_t)s * OUT_DIM))[hl];
                float4 yl = bf4(p.x, p.y), yh = bf4(p.z, p.w);
                accl.x += w * yl.x; accl.y += w * yl.y; accl.z += w * yl.z; accl.w += w * yl.w;
                acch.x += w * yh.x; acch.y += w * yh.y; acch.z += w * yh.z; acch.w += w * yh.w;
                den += w;
            }
        }
    }
    float rd = 1.f / den;
    float o[8] = {accl.x * rd, accl.y * rd, accl.z * rd, accl.w * rd,
                  acch.x * rd, acch.y * rd, acch.z * rd, acch.w * rd};
#pragma unroll
    for (int j = 0; j < 8; ++j) o[j] = fmaxf(o[j], 0.f);
    size_t idx = (size_t)d * OUT_DIM + hl * 8;
    if (isb) {
        u16 pk[8];
#pragma unroll
        for (int j = 0; j < 8; ++j) pk[j] = f2bf(o[j]);
        *(uint4*)((u16*)out + idx) = *(const uint4*)pk;
    } else {
        float* op = (float*)out + idx;
        *(float4*)op = *(const float4*)&o[0];
        *(float4*)(op + 4) = *(const float4*)&o[4];
    }
}

extern "C" void kernel_launch(void* const* d_in, const int* in_sizes, int n_in,
                              void* d_out, int out_size, void* d_ws, size_t ws_size,
                              hipStream_t stream) {
    const void* x    = d_in[0];
    const void* eidx = d_in[1];
    const void* W    = d_in[2];
    const void* as   = d_in[3];
    const void* ad   = d_in[4];
    int n = in_sizes[0] / IN_DIM;   // 50000
    int E = in_sizes[1] / 2;        // 800000

    char* ws = (char*)d_ws;
    size_t off_b = 0;
    auto alloc = [&](size_t bytes) -> void* {
        void* p = ws + off_b;
        off_b += (bytes + 255) & ~(size_t)255;
        return p;
    };
    u16*   Wtb    = (u16*)alloc((size_t)IN_DIM * OUT_DIM * 2);
    float* asf    = (float*)alloc(256 * 4);
    float* adf    = (float*)alloc(256 * 4);
    u16*   xpb    = (u16*)alloc((size_t)n * OUT_DIM * 2);
    float* a_src  = (float*)alloc((size_t)n * NHEADS * 4);
    float* a_dst  = (float*)alloc((size_t)n * NHEADS * 4);
    int*   cnt    = (int*)alloc((size_t)(n + 1) * 4);   // +1: overflow counter
    int*   ell    = (int*)alloc((size_t)n * ELLW * 4);
    int*   ovf    = (int*)alloc((size_t)OVFCAP * 8);

    int ngemm = (n + 127) / 128;        // 391
    int nell  = (E + 255) / 256;        // 3125
    int nzero = (n + 1 + 255) / 256;    // 196

    hipLaunchKernelGGL(k_conv, dim3(129 + nzero), dim3(256), 0, stream,
                       x, W, as, ad, Wtb, asf, adf, cnt, n);
    hipLaunchKernelGGL(k_main, dim3(ngemm + nell), dim3(256), 0, stream,
                       x, eidx, Wtb, asf, adf, xpb, a_src, a_dst, cnt, ell, ovf, n, E, ngemm);
    int nwave = (n + 1) / 2;
    hipLaunchKernelGGL(k_agg, dim3((nwave + 3) / 4), dim3(256), 0, stream,
                       cnt, ell, ovf, a_src, a_dst, xpb, d_out, x, n);
}